// Round 1
// baseline (220.681 us; speedup 1.0000x reference)
//
#include <hip/hip_runtime.h>
#include <hip/hip_bf16.h>
#include <stdint.h>

// ---------------------------------------------------------------------------
// QNN forward:
//   angles = x@W^T + b                                  (k_embed, phase 1)
//   E[b][i] = prod_w cs[w][bit_{9-w}(i)]   (product state after RY embedding)
//   U = fixed 1024x1024 unitary of the 20 entangling layers (k_usim: per-column
//       LDS simulation; CNOTs folded into GF(2) index-bit tracking, so only the
//       200 Rot gates move data)
//   out[b][p<784] = clip(|sum_k U[p][k] E[b][k]|^2 * 784, 0, 1)
//       -> one f16 MFMA GEMM  C[8192][1568] = E @ Bt^T  with re/im interleaved
//          in adjacent columns and the |.|^2 epilogue fused via shfl_xor(1).
// ---------------------------------------------------------------------------

#define NWIRES  10
#define DIM     1024
#define NLAYERS 20
#define NGATES  200
#define PIXELS  784

typedef _Float16 f16;
typedef _Float16 f16x8 __attribute__((ext_vector_type(8)));
typedef float    f32x4 __attribute__((ext_vector_type(4)));

typedef const __attribute__((address_space(1))) void* gas1_t;
typedef __attribute__((address_space(3))) void*       las3_t;

__device__ __forceinline__ void gload_lds16(const void* g, void* l) {
  __builtin_amdgcn_global_load_lds((gas1_t)g, (las3_t)l, 16, 0, 0);
}

// ---------------------------------------------------------------------------
// Kernel 1: linear layer + RY product-state embedding. One block per batch row.
// ---------------------------------------------------------------------------
__global__ __launch_bounds__(256) void k_embed(const float* __restrict__ x,
                                               const float* __restrict__ W,
                                               const float* __restrict__ bias,
                                               f16* __restrict__ E) {
  const int b   = blockIdx.x;
  const int tid = threadIdx.x;
  const float* xr = x + (size_t)b * PIXELS;

  float acc[NWIRES];
#pragma unroll
  for (int w = 0; w < NWIRES; w++) acc[w] = 0.f;

  for (int k = tid; k < PIXELS; k += 256) {
    float xv = xr[k];
#pragma unroll
    for (int w = 0; w < NWIRES; w++) acc[w] = fmaf(xv, W[w * PIXELS + k], acc[w]);
  }

#pragma unroll
  for (int w = 0; w < NWIRES; w++) {
    float v = acc[w];
#pragma unroll
    for (int off = 32; off > 0; off >>= 1) v += __shfl_xor(v, off, 64);
    acc[w] = v;
  }

  __shared__ float part[4][NWIRES];
  __shared__ float csh[NWIRES][2];
  const int wv = tid >> 6, ln = tid & 63;
  if (ln == 0) {
#pragma unroll
    for (int w = 0; w < NWIRES; w++) part[wv][w] = acc[w];
  }
  __syncthreads();
  if (tid < NWIRES) {
    float a = part[0][tid] + part[1][tid] + part[2][tid] + part[3][tid] + bias[tid];
    float s, c;
    sincosf(0.5f * a, &s, &c);
    csh[tid][0] = c;
    csh[tid][1] = s;
  }
  __syncthreads();

  __align__(8) f16 e4[4];
#pragma unroll
  for (int u = 0; u < 4; u++) {
    int i = tid * 4 + u;
    float pr = 1.f;
#pragma unroll
    for (int w = 0; w < NWIRES; w++) pr *= csh[w][(i >> (9 - w)) & 1];
    e4[u] = (f16)pr;
  }
  *(uint2*)(&E[(size_t)b * DIM + tid * 4]) = *(const uint2*)e4;
}

// ---------------------------------------------------------------------------
// Kernel 2: simulate the fixed circuit on the identity -> U, one column/block.
// CNOTs are GF(2)-linear on index bits: track A (storage->logical map) rows for
// parity selection and A^{-1} columns as pair XOR masks; no data movement.
// Output W1[k][2i]=Re U[i][k], W1[k][2i+1]=Im U[i][k]  (row k = storage column).
// ---------------------------------------------------------------------------
__global__ __launch_bounds__(256) void k_usim(const float* __restrict__ qw,
                                              f16* __restrict__ W1) {
  __shared__ float2   st[DIM];               // 8 KiB state column (fp32 complex)
  __shared__ float    gm[NGATES][8];         // Rot matrices (complex 2x2)
  __shared__ unsigned sh_rowA[NWIRES];       // rows of A
  __shared__ unsigned sh_invc[NWIRES];       // columns of A^{-1}

  const int tid = threadIdx.x;
  const int col = blockIdx.x;

  // Rot(phi,theta,omega) = RZ(om) RY(th) RZ(phi):
  //   m00 = e^{-i(phi+om)/2} c   m01 = -e^{+i(phi-om)/2} s
  //   m10 = e^{-i(phi-om)/2} s   m11 = e^{+i(phi+om)/2} c
  if (tid < NGATES) {
    float phi = qw[tid * 3 + 0], th = qw[tid * 3 + 1], om = qw[tid * 3 + 2];
    float s, c, sa, ca, sb, cb;
    sincosf(0.5f * th, &s, &c);
    sincosf(0.5f * (phi + om), &sa, &ca);
    sincosf(0.5f * (phi - om), &sb, &cb);
    gm[tid][0] = ca * c;  gm[tid][1] = -sa * c;   // m00
    gm[tid][2] = -cb * s; gm[tid][3] = -sb * s;   // m01
    gm[tid][4] = cb * s;  gm[tid][5] = -sb * s;   // m10
    gm[tid][6] = ca * c;  gm[tid][7] = sa * c;    // m11
  }
  if (tid < NWIRES) {
    sh_rowA[tid] = 1u << tid;
    sh_invc[tid] = 1u << tid;
  }
  for (int i = tid; i < DIM; i += 256)
    st[i] = make_float2(i == col ? 1.f : 0.f, 0.f);
  __syncthreads();

  for (int l = 0; l < NLAYERS; l++) {
    for (int w = 0; w < NWIRES; w++) {
      const int p = 9 - w;                     // wire w <-> logical bit 9-w
      const int g = l * NWIRES + w;
      const unsigned sels = sh_rowA[p];        // parity mask: logical bit p of A(j)
      const unsigned mks  = sh_invc[p];        // pair mask:   A^{-1} e_p
      const float m00r = gm[g][0], m00i = gm[g][1];
      const float m01r = gm[g][2], m01i = gm[g][3];
      const float m10r = gm[g][4], m10i = gm[g][5];
      const float m11r = gm[g][6], m11i = gm[g][7];
      const unsigned b    = sels & (0u - sels);  // pivot bit (lowest set in sels)
      const unsigned lowm = b - 1u;

#pragma unroll
      for (int it = 0; it < 2; it++) {
        unsigned q  = (unsigned)tid + (unsigned)it * 256u;        // pair id, 0..511
        unsigned j0 = ((q & ~lowm) << 1) | (q & lowm);            // insert 0 at pivot
        unsigned j  = j0 | ((__popc(sels & j0) & 1) ? b : 0u);    // parity(sels&j)==0
        unsigned jp = j ^ mks;                                    // partner (bit p = 1)
        float2 a0 = st[j], a1 = st[jp];
        float2 r0, r1;
        r0.x = m00r * a0.x - m00i * a0.y + m01r * a1.x - m01i * a1.y;
        r0.y = m00r * a0.y + m00i * a0.x + m01r * a1.y + m01i * a1.x;
        r1.x = m10r * a0.x - m10i * a0.y + m11r * a1.x - m11i * a1.y;
        r1.y = m10r * a0.y + m10i * a0.x + m11r * a1.y + m11i * a1.x;
        st[j]  = r0;
        st[jp] = r1;
      }
      __syncthreads();
    }
    // CNOT ring of this layer: A <- C*A (row_pt ^= row_pc), A^{-1} <- A^{-1}*C
    if (tid == 0) {
      int r = (l % (NWIRES - 1)) + 1;
#pragma unroll
      for (int w = 0; w < NWIRES; w++) {
        int c = w, t = (w + r) % NWIRES;
        int pc = 9 - c, pt = 9 - t;
        sh_rowA[pt] ^= sh_rowA[pc];
        sh_invc[pc] ^= sh_invc[pt];
      }
    }
    __syncthreads();
  }

  // write out: logical row i lives at storage j = XOR of inv columns of set bits
  unsigned invl[NWIRES];
#pragma unroll
  for (int p = 0; p < NWIRES; p++) invl[p] = sh_invc[p];

  __align__(16) f16 o8[8];
#pragma unroll
  for (int u = 0; u < 4; u++) {
    int i = tid * 4 + u;
    unsigned j = 0;
#pragma unroll
    for (int p = 0; p < NWIRES; p++)
      if ((i >> p) & 1) j ^= invl[p];
    float2 v = st[j];
    o8[2 * u]     = (f16)v.x;
    o8[2 * u + 1] = (f16)v.y;
  }
  *(uint4*)(&W1[(size_t)col * 2048 + tid * 8]) = *(const uint4*)o8;
}

// ---------------------------------------------------------------------------
// Kernel 3: transpose W1[1024][2048] -> Bt[2048][1024] (f16), LDS-tiled.
// ---------------------------------------------------------------------------
__global__ __launch_bounds__(256) void k_transpose(const f16* __restrict__ W1,
                                                   f16* __restrict__ Bt) {
  __shared__ f16 tile[64][65];
  const int bx  = blockIdx.x;   // n-tile: 0..31
  const int by  = blockIdx.y;   // k-tile: 0..15
  const int tid = threadIdx.x;
#pragma unroll
  for (int e = 0; e < 16; e++) {
    int idx = e * 256 + tid;
    int r = idx >> 6, c = idx & 63;
    tile[r][c] = W1[(size_t)(by * 64 + r) * 2048 + bx * 64 + c];
  }
  __syncthreads();
#pragma unroll
  for (int e = 0; e < 16; e++) {
    int idx = e * 256 + tid;
    int rn = idx >> 6, ck = idx & 63;
    Bt[(size_t)(bx * 64 + rn) * 1024 + by * 64 + ck] = tile[ck][rn];
  }
}

// ---------------------------------------------------------------------------
// Kernel 4: C = E[8192][1024] @ Bt^T, f16 MFMA 16x16x32, 128x128 tile, BK=64,
// fused |re|^2+|im|^2 epilogue (re/im in adjacent n columns).
// ---------------------------------------------------------------------------
__global__ __launch_bounds__(256) void k_gemm(const f16* __restrict__ E,
                                              const f16* __restrict__ Bt,
                                              float* __restrict__ out) {
  __shared__ __align__(16) f16 As[128 * 64];
  __shared__ __align__(16) f16 Bs[128 * 64];

  const int tid = threadIdx.x;
  const int wv = tid >> 6, ln = tid & 63;
  const int wr = wv >> 1, wc = wv & 1;
  const int m0 = blockIdx.x * 128;
  const int n0 = blockIdx.y * 128;

  f32x4 acc[4][4];
#pragma unroll
  for (int a = 0; a < 4; a++)
#pragma unroll
    for (int q = 0; q < 4; q++) acc[a][q] = (f32x4){0.f, 0.f, 0.f, 0.f};

  for (int kt = 0; kt < 16; kt++) {
#pragma unroll
    for (int r = 0; r < 4; r++) {
      int ub  = (r * 4 + wv) * 64;        // wave-uniform 16B-unit base
      int u   = ub + ln;                  // this lane's unit
      int row = u >> 3;
      int cb  = (u & 7) * 16;
      const char* gA = (const char*)E  + ((size_t)(m0 + row) * 2048) + kt * 128 + cb;
      const char* gB = (const char*)Bt + ((size_t)(n0 + row) * 2048) + kt * 128 + cb;
      gload_lds16(gA, (char*)As + (size_t)ub * 16);
      gload_lds16(gB, (char*)Bs + (size_t)ub * 16);
    }
    __syncthreads();

#pragma unroll
    for (int ks = 0; ks < 2; ks++) {
      f16x8 af[4], bf[4];
#pragma unroll
      for (int mi = 0; mi < 4; mi++)
        af[mi] = *(const f16x8*)&As[(wr * 64 + mi * 16 + (ln & 15)) * 64 + ks * 32 + (ln >> 4) * 8];
#pragma unroll
      for (int ni = 0; ni < 4; ni++)
        bf[ni] = *(const f16x8*)&Bs[(wc * 64 + ni * 16 + (ln & 15)) * 64 + ks * 32 + (ln >> 4) * 8];
#pragma unroll
      for (int mi = 0; mi < 4; mi++)
#pragma unroll
        for (int ni = 0; ni < 4; ni++)
          acc[mi][ni] = __builtin_amdgcn_mfma_f32_16x16x32_f16(af[mi], bf[ni], acc[mi][ni], 0, 0, 0);
    }
    __syncthreads();
  }

  // epilogue: n even = Re, n odd = Im (adjacent lanes); p = n>>1
#pragma unroll
  for (int mi = 0; mi < 4; mi++) {
#pragma unroll
    for (int ni = 0; ni < 4; ni++) {
      int nbase = n0 + wc * 64 + ni * 16 + (ln & 15);
      int p = nbase >> 1;
      bool even = (ln & 1) == 0;
#pragma unroll
      for (int r = 0; r < 4; r++) {
        float v = acc[mi][ni][r];
        float o = __shfl_xor(v, 1, 64);
        if (even && p < PIXELS) {
          int m = m0 + wr * 64 + mi * 16 + (ln >> 4) * 4 + r;
          float s2 = (v * v + o * o) * (float)PIXELS;
          out[(size_t)m * PIXELS + p] = fminf(fmaxf(s2, 0.f), 1.f);
        }
      }
    }
  }
}

// ---------------------------------------------------------------------------
extern "C" void kernel_launch(void* const* d_in, const int* in_sizes, int n_in,
                              void* d_out, int out_size, void* d_ws, size_t ws_size,
                              hipStream_t stream) {
  const float* x    = (const float*)d_in[0];
  const float* W    = (const float*)d_in[1];
  const float* bias = (const float*)d_in[2];
  const float* qw   = (const float*)d_in[3];
  float* out        = (float*)d_out;

  char* ws = (char*)d_ws;
  f16* E  = (f16*)(ws);                                  // 16 MiB: [8192][1024]
  f16* W1 = (f16*)(ws + (size_t)16 * 1024 * 1024);       //  4 MiB: [1024][2048]
  f16* Bt = (f16*)(ws + (size_t)20 * 1024 * 1024);       //  4 MiB: [2048][1024]

  k_embed<<<dim3(8192), dim3(256), 0, stream>>>(x, W, bias, E);
  k_usim<<<dim3(1024), dim3(256), 0, stream>>>(qw, W1);
  k_transpose<<<dim3(32, 16), dim3(256), 0, stream>>>(W1, Bt);
  k_gemm<<<dim3(64, 13), dim3(256), 0, stream>>>(E, Bt, out);
}

// Round 2
// 166.099 us; speedup vs baseline: 1.3286x; 1.3286x over previous
//
#include <hip/hip_runtime.h>
#include <hip/hip_bf16.h>
#include <stdint.h>

// ---------------------------------------------------------------------------
// QNN forward:
//   angles = x@W^T + b                                  (k_embed)
//   E[b][i] = prod_w cs[w][bit_{9-w}(i)]   (product state after RY embedding)
//   U = fixed 1024x1024 unitary of the 20 entangling layers:
//     k_prep: fold CNOT rings into GF(2) index-bit tracking; fuse each layer's
//             10 Rot gates into 5 precomputed 4x4 complex matrices + coset
//             params (all block-invariant -> scalar loads in k_usim).
//     k_usim: one column per block, 100 quad-passes over an 8KB LDS state.
//   out[b][p<784] = clip(|sum_k U[p][k] E[b][k]|^2 * 784, 0, 1)
//       -> one f16 MFMA GEMM  C[8192][1568] = E @ Bt^T  with re/im interleaved
//          in adjacent columns and the |.|^2 epilogue fused via shfl_xor(1).
// ---------------------------------------------------------------------------

#define NWIRES  10
#define DIM     1024
#define NLAYERS 20
#define NGATES  200
#define NPASS   100
#define PIXELS  784

typedef _Float16 f16;
typedef _Float16 f16x8 __attribute__((ext_vector_type(8)));
typedef float    f32x4 __attribute__((ext_vector_type(4)));

typedef const __attribute__((address_space(1))) void* gas1_t;
typedef __attribute__((address_space(3))) void*       las3_t;

__device__ __forceinline__ void gload_lds16(const void* g, void* l) {
  __builtin_amdgcn_global_load_lds((gas1_t)g, (las3_t)l, 16, 0, 0);
}

// ---------------------------------------------------------------------------
// Kernel 1: linear layer + RY product-state embedding. One block per batch row.
// ---------------------------------------------------------------------------
__global__ __launch_bounds__(256) void k_embed(const float* __restrict__ x,
                                               const float* __restrict__ W,
                                               const float* __restrict__ bias,
                                               f16* __restrict__ E) {
  const int b   = blockIdx.x;
  const int tid = threadIdx.x;
  const float* xr = x + (size_t)b * PIXELS;

  float acc[NWIRES];
#pragma unroll
  for (int w = 0; w < NWIRES; w++) acc[w] = 0.f;

  for (int k = tid; k < PIXELS; k += 256) {
    float xv = xr[k];
#pragma unroll
    for (int w = 0; w < NWIRES; w++) acc[w] = fmaf(xv, W[w * PIXELS + k], acc[w]);
  }

#pragma unroll
  for (int w = 0; w < NWIRES; w++) {
    float v = acc[w];
#pragma unroll
    for (int off = 32; off > 0; off >>= 1) v += __shfl_xor(v, off, 64);
    acc[w] = v;
  }

  __shared__ float part[4][NWIRES];
  __shared__ float csh[NWIRES][2];
  const int wv = tid >> 6, ln = tid & 63;
  if (ln == 0) {
#pragma unroll
    for (int w = 0; w < NWIRES; w++) part[wv][w] = acc[w];
  }
  __syncthreads();
  if (tid < NWIRES) {
    float a = part[0][tid] + part[1][tid] + part[2][tid] + part[3][tid] + bias[tid];
    float s, c;
    sincosf(0.5f * a, &s, &c);
    csh[tid][0] = c;
    csh[tid][1] = s;
  }
  __syncthreads();

  __align__(8) f16 e4[4];
#pragma unroll
  for (int u = 0; u < 4; u++) {
    int i = tid * 4 + u;
    float pr = 1.f;
#pragma unroll
    for (int w = 0; w < NWIRES; w++) pr *= csh[w][(i >> (9 - w)) & 1];
    e4[u] = (f16)pr;
  }
  *(uint2*)(&E[(size_t)b * DIM + tid * 4]) = *(const uint2*)e4;
}

// ---------------------------------------------------------------------------
// Kernel 2a: plan precompute (1 block).
//  - threads 0..199: Rot 2x2 complex matrices into LDS
//  - thread 0: GF(2) evolution of (rowA, invc) across the 20 CNOT rings;
//              per pass: eliminated selectors/pivots + pair masks -> plan_idx
//  - threads 100..199: 4x4 kron matrices per (layer, wire-pair) -> plan_mat
// ---------------------------------------------------------------------------
__global__ __launch_bounds__(256) void k_prep(const float* __restrict__ qw,
                                              float* __restrict__ plan_mat,
                                              unsigned* __restrict__ plan_idx,
                                              unsigned* __restrict__ plan_final) {
  __shared__ float gm[NGATES][8];
  const int tid = threadIdx.x;

  // Rot(phi,theta,omega) = RZ(om) RY(th) RZ(phi):
  //   m00 = e^{-i(phi+om)/2} c   m01 = -e^{+i(phi-om)/2} s
  //   m10 = e^{-i(phi-om)/2} s   m11 = e^{+i(phi+om)/2} c
  if (tid < NGATES) {
    float phi = qw[tid * 3 + 0], th = qw[tid * 3 + 1], om = qw[tid * 3 + 2];
    float s, c, sa, ca, sb, cb;
    sincosf(0.5f * th, &s, &c);
    sincosf(0.5f * (phi + om), &sa, &ca);
    sincosf(0.5f * (phi - om), &sb, &cb);
    gm[tid][0] = ca * c;  gm[tid][1] = -sa * c;   // m00
    gm[tid][2] = -cb * s; gm[tid][3] = -sb * s;   // m01
    gm[tid][4] = cb * s;  gm[tid][5] = -sb * s;   // m10
    gm[tid][6] = ca * c;  gm[tid][7] = sa * c;    // m11
  }
  __syncthreads();

  if (tid == 0) {
    unsigned rowA[NWIRES], invc[NWIRES];
    for (int i = 0; i < NWIRES; i++) { rowA[i] = 1u << i; invc[i] = 1u << i; }
    for (int l = 0; l < NLAYERS; l++) {
      for (int s = 0; s < 5; s++) {
        int w1 = 2 * s, w2 = 2 * s + 1;
        int p1 = 9 - w1, p2 = 9 - w2;
        unsigned u1 = rowA[p1], u2 = rowA[p2];
        unsigned m1 = invc[p1], m2 = invc[p2];
        // 2-row GF(2) elimination to echelon (b1 in u1 only, b2 in u2 only)
        unsigned b1 = u1 & (0u - u1);
        if (u2 & b1) u2 ^= u1;
        unsigned b2 = u2 & (0u - u2);
        if (u1 & b2) u1 ^= u2;
        unsigned bLo = (b1 < b2) ? b1 : b2;
        unsigned bHi = (b1 < b2) ? b2 : b1;
        unsigned* P = plan_idx + (size_t)(l * 5 + s) * 8;
        P[0] = bLo; P[1] = bHi; P[2] = u1; P[3] = u2;
        P[4] = b1;  P[5] = b2;  P[6] = m1; P[7] = m2;
      }
      int r = (l % (NWIRES - 1)) + 1;
      for (int w = 0; w < NWIRES; w++) {
        int c = w, t = (w + r) % NWIRES;
        int pc = 9 - c, pt = 9 - t;
        rowA[pt] ^= rowA[pc];
        invc[pc] ^= invc[pt];
      }
    }
    for (int p = 0; p < NWIRES; p++) plan_final[p] = invc[p];
  } else if (tid >= 100 && tid < 200) {
    int t = tid - 100;
    int l = t / 5, s = t % 5;
    int g1 = l * NWIRES + 2 * s, g2 = g1 + 1;
    float* K = plan_mat + (size_t)t * 32;
#pragma unroll
    for (int r = 0; r < 4; r++) {
#pragma unroll
      for (int c = 0; c < 4; c++) {
        int r1 = r >> 1, c1 = c >> 1, r2 = r & 1, c2 = c & 1;
        float ar = gm[g1][(r1 * 2 + c1) * 2], ai = gm[g1][(r1 * 2 + c1) * 2 + 1];
        float br = gm[g2][(r2 * 2 + c2) * 2], bi = gm[g2][(r2 * 2 + c2) * 2 + 1];
        K[(r * 4 + c) * 2]     = ar * br - ai * bi;
        K[(r * 4 + c) * 2 + 1] = ar * bi + ai * br;
      }
    }
  }
}

// ---------------------------------------------------------------------------
// Kernel 2b: simulate the fixed circuit on the identity -> U, one column/block.
// 100 quad-passes; each thread owns one disjoint quad (4 reads, 4x4 complex
// matvec from scalar-loaded plan, 4 writes); one barrier per pass.
// Output W1[k][2i]=Re U[i][k], W1[k][2i+1]=Im U[i][k]  (row k = storage column).
// ---------------------------------------------------------------------------
__global__ __launch_bounds__(256) void k_usim(const float* __restrict__ plan_mat,
                                              const unsigned* __restrict__ plan_idx,
                                              const unsigned* __restrict__ plan_final,
                                              f16* __restrict__ W1) {
  __shared__ float2 st[DIM];
  const int tid = threadIdx.x;
  const int col = blockIdx.x;

  for (int i = tid; i < DIM; i += 256)
    st[i] = make_float2(i == col ? 1.f : 0.f, 0.f);
  __syncthreads();

  for (int t = 0; t < NPASS; t++) {
    const unsigned* P = plan_idx + (size_t)t * 8;
    const unsigned bLo = P[0], bHi = P[1], u1 = P[2], u2 = P[3];
    const unsigned pb1 = P[4], pb2 = P[5], m1 = P[6], m2 = P[7];
    const float* Kp = plan_mat + (size_t)t * 32;

    // coset representative: insert 0-bits at bLo,bHi, then fix both parities
    unsigned q  = (unsigned)tid;
    unsigned x  = ((q & ~(bLo - 1u)) << 1) | (q & (bLo - 1u));
    unsigned j0 = ((x & ~(bHi - 1u)) << 1) | (x & (bHi - 1u));
    unsigned j  = j0 ^ ((__popc(u1 & j0) & 1) ? pb1 : 0u)
                     ^ ((__popc(u2 & j0) & 1) ? pb2 : 0u);

    float2 v0 = st[j];
    float2 v1 = st[j ^ m2];
    float2 v2 = st[j ^ m1];
    float2 v3 = st[j ^ m1 ^ m2];

#define KR(idx) Kp[(idx) * 2]
#define KI(idx) Kp[(idx) * 2 + 1]
#define ACC(rr, idx, vv)                                      \
    rr.x = fmaf(KR(idx), vv.x, fmaf(-KI(idx), vv.y, rr.x));   \
    rr.y = fmaf(KR(idx), vv.y, fmaf(KI(idx), vv.x, rr.y));

    float2 r0 = {0.f, 0.f}, r1 = {0.f, 0.f}, r2 = {0.f, 0.f}, r3 = {0.f, 0.f};
    ACC(r0, 0, v0)  ACC(r0, 1, v1)  ACC(r0, 2, v2)  ACC(r0, 3, v3)
    ACC(r1, 4, v0)  ACC(r1, 5, v1)  ACC(r1, 6, v2)  ACC(r1, 7, v3)
    ACC(r2, 8, v0)  ACC(r2, 9, v1)  ACC(r2, 10, v2) ACC(r2, 11, v3)
    ACC(r3, 12, v0) ACC(r3, 13, v1) ACC(r3, 14, v2) ACC(r3, 15, v3)
#undef ACC
#undef KR
#undef KI

    st[j]           = r0;
    st[j ^ m2]      = r1;
    st[j ^ m1]      = r2;
    st[j ^ m1 ^ m2] = r3;
    __syncthreads();
  }

  // write out: logical row i lives at storage j = XOR of inv columns of set bits
  unsigned invl[NWIRES];
#pragma unroll
  for (int p = 0; p < NWIRES; p++) invl[p] = plan_final[p];

  __align__(16) f16 o8[8];
#pragma unroll
  for (int u = 0; u < 4; u++) {
    int i = tid * 4 + u;
    unsigned j = 0;
#pragma unroll
    for (int p = 0; p < NWIRES; p++)
      if ((i >> p) & 1) j ^= invl[p];
    float2 v = st[j];
    o8[2 * u]     = (f16)v.x;
    o8[2 * u + 1] = (f16)v.y;
  }
  *(uint4*)(&W1[(size_t)col * 2048 + tid * 8]) = *(const uint4*)o8;
}

// ---------------------------------------------------------------------------
// Kernel 3: transpose W1[1024][2048] -> Bt[2048][1024] (f16), LDS-tiled.
// ---------------------------------------------------------------------------
__global__ __launch_bounds__(256) void k_transpose(const f16* __restrict__ W1,
                                                   f16* __restrict__ Bt) {
  __shared__ f16 tile[64][65];
  const int bx  = blockIdx.x;   // n-tile: 0..31
  const int by  = blockIdx.y;   // k-tile: 0..15
  const int tid = threadIdx.x;
#pragma unroll
  for (int e = 0; e < 16; e++) {
    int idx = e * 256 + tid;
    int r = idx >> 6, c = idx & 63;
    tile[r][c] = W1[(size_t)(by * 64 + r) * 2048 + bx * 64 + c];
  }
  __syncthreads();
#pragma unroll
  for (int e = 0; e < 16; e++) {
    int idx = e * 256 + tid;
    int rn = idx >> 6, ck = idx & 63;
    Bt[(size_t)(bx * 64 + rn) * 1024 + by * 64 + ck] = tile[ck][rn];
  }
}

// ---------------------------------------------------------------------------
// Kernel 4: C = E[8192][1024] @ Bt^T, f16 MFMA 16x16x32, 128x128 tile, BK=64,
// fused |re|^2+|im|^2 epilogue (re/im in adjacent n columns).
// ---------------------------------------------------------------------------
__global__ __launch_bounds__(256) void k_gemm(const f16* __restrict__ E,
                                              const f16* __restrict__ Bt,
                                              float* __restrict__ out) {
  __shared__ __align__(16) f16 As[128 * 64];
  __shared__ __align__(16) f16 Bs[128 * 64];

  const int tid = threadIdx.x;
  const int wv = tid >> 6, ln = tid & 63;
  const int wr = wv >> 1, wc = wv & 1;
  const int m0 = blockIdx.x * 128;
  const int n0 = blockIdx.y * 128;

  f32x4 acc[4][4];
#pragma unroll
  for (int a = 0; a < 4; a++)
#pragma unroll
    for (int q = 0; q < 4; q++) acc[a][q] = (f32x4){0.f, 0.f, 0.f, 0.f};

  for (int kt = 0; kt < 16; kt++) {
#pragma unroll
    for (int r = 0; r < 4; r++) {
      int ub  = (r * 4 + wv) * 64;        // wave-uniform 16B-unit base
      int u   = ub + ln;                  // this lane's unit
      int row = u >> 3;
      int cb  = (u & 7) * 16;
      const char* gA = (const char*)E  + ((size_t)(m0 + row) * 2048) + kt * 128 + cb;
      const char* gB = (const char*)Bt + ((size_t)(n0 + row) * 2048) + kt * 128 + cb;
      gload_lds16(gA, (char*)As + (size_t)ub * 16);
      gload_lds16(gB, (char*)Bs + (size_t)ub * 16);
    }
    __syncthreads();

#pragma unroll
    for (int ks = 0; ks < 2; ks++) {
      f16x8 af[4], bf[4];
#pragma unroll
      for (int mi = 0; mi < 4; mi++)
        af[mi] = *(const f16x8*)&As[(wr * 64 + mi * 16 + (ln & 15)) * 64 + ks * 32 + (ln >> 4) * 8];
#pragma unroll
      for (int ni = 0; ni < 4; ni++)
        bf[ni] = *(const f16x8*)&Bs[(wc * 64 + ni * 16 + (ln & 15)) * 64 + ks * 32 + (ln >> 4) * 8];
#pragma unroll
      for (int mi = 0; mi < 4; mi++)
#pragma unroll
        for (int ni = 0; ni < 4; ni++)
          acc[mi][ni] = __builtin_amdgcn_mfma_f32_16x16x32_f16(af[mi], bf[ni], acc[mi][ni], 0, 0, 0);
    }
    __syncthreads();
  }

  // epilogue: n even = Re, n odd = Im (adjacent lanes); p = n>>1
#pragma unroll
  for (int mi = 0; mi < 4; mi++) {
#pragma unroll
    for (int ni = 0; ni < 4; ni++) {
      int nbase = n0 + wc * 64 + ni * 16 + (ln & 15);
      int p = nbase >> 1;
      bool even = (ln & 1) == 0;
#pragma unroll
      for (int r = 0; r < 4; r++) {
        float v = acc[mi][ni][r];
        float o = __shfl_xor(v, 1, 64);
        if (even && p < PIXELS) {
          int m = m0 + wr * 64 + mi * 16 + (ln >> 4) * 4 + r;
          float s2 = (v * v + o * o) * (float)PIXELS;
          out[(size_t)m * PIXELS + p] = fminf(fmaxf(s2, 0.f), 1.f);
        }
      }
    }
  }
}

// ---------------------------------------------------------------------------
extern "C" void kernel_launch(void* const* d_in, const int* in_sizes, int n_in,
                              void* d_out, int out_size, void* d_ws, size_t ws_size,
                              hipStream_t stream) {
  const float* x    = (const float*)d_in[0];
  const float* W    = (const float*)d_in[1];
  const float* bias = (const float*)d_in[2];
  const float* qw   = (const float*)d_in[3];
  float* out        = (float*)d_out;

  char* ws = (char*)d_ws;
  f16* E  = (f16*)(ws);                                   // 16 MiB: [8192][1024]
  f16* W1 = (f16*)(ws + (size_t)16 * 1024 * 1024);        //  4 MiB: [1024][2048]
  f16* Bt = (f16*)(ws + (size_t)20 * 1024 * 1024);        //  4 MiB: [2048][1024]
  float*    plan_mat   = (float*)(ws + (size_t)24 * 1024 * 1024);            // 12.8 KB
  unsigned* plan_idx   = (unsigned*)(ws + (size_t)24 * 1024 * 1024 + 65536); //  3.2 KB
  unsigned* plan_final = (unsigned*)(ws + (size_t)24 * 1024 * 1024 + 131072);//  40 B

  k_prep<<<dim3(1), dim3(256), 0, stream>>>(qw, plan_mat, plan_idx, plan_final);
  k_embed<<<dim3(8192), dim3(256), 0, stream>>>(x, W, bias, E);
  k_usim<<<dim3(1024), dim3(256), 0, stream>>>(plan_mat, plan_idx, plan_final, W1);
  k_transpose<<<dim3(32, 16), dim3(256), 0, stream>>>(W1, Bt);
  k_gemm<<<dim3(64, 13), dim3(256), 0, stream>>>(E, Bt, out);
}